// Round 15
// baseline (134.362 us; speedup 1.0000x reference)
//
#include <hip/hip_runtime.h>

// Sinkhorn fixed-point for fermionic canonical ensembles.
// B=2048 systems, P=64 orbitals, N_PART=32, n_iters from d_in[2].
//
// R14 = R13 with the compile fix (float4 v4A/v4B, was mistyped float).
// R13 theory: PHASE-PARALLEL PACK-2. R12's neutrality proved the compiler
// already fills intra-system stall slots, so R11's remaining ~3100
// stall-cyc/iter are structural: one system's phases form a serial chain
// and 1 wave/SIMD has no second stream. Fix: one wave owns 2 systems, each
// using the FULL 64-lane R10 mappings, loop body duplicated (A; B). The
// two dataflow graphs are independent -> scheduler interleaves A's
// chain-bound sweep with B's issue-bound C-block and vice versa.
// Per-system fp sequences are VERBATIM R10/R12 (both passed, 0.015625).
// CANARY: absmax must be exactly 0.015625.
// Posture: contract(off), Cody-Waite exp/log, ~1ulp rcp_nr, Er preload +
// volatile pins, waves_per_eu(1,1), barrier-bracketed LDS staging.

#pragma clang fp contract(off)

#define NPART 32
#define PORB  64

#define L2E_HI 1.44269502162933349609375f
#define L2E_LO 1.9259629911266175e-08f
#define LN2_HI 0.69314718246459960938f
#define LN2_LO -1.9046542121259175e-09f
#define LN2F   0.6931471805599453f

__device__ __forceinline__ float readlane_f(float v, int srclane) {
    return __int_as_float(__builtin_amdgcn_readlane(__float_as_int(v), srclane));
}

// reciprocal: v_rcp_f32 + one Newton step => ~0.5-1 ulp
__device__ __forceinline__ float rcp_nr(float d) {
    float r = __builtin_amdgcn_rcpf(d);
    float e = fmaf(-d, r, 1.0f);
    return fmaf(r, e, r);
}

// e^arg with Cody-Waite correction (<=1.5 ulp), arg pre-rounded like numpy
__device__ __forceinline__ float exp_acc(float arg) {
    float p    = arg * L2E_HI;
    float perr = fmaf(arg, L2E_HI, -p);
    float c    = fmaf(arg, L2E_LO, perr);
    float e0   = __builtin_amdgcn_exp2f(p);
    return fmaf(e0, c * LN2F, e0);
}

// ln(x) = log2(x)*ln2 with split constant (~1.5 ulp)
__device__ __forceinline__ float ln_acc(float x) {
    float l2 = __log2f(x);
    float p  = l2 * LN2_HI;
    float e  = fmaf(l2, LN2_HI, -p);
    return p + fmaf(l2, LN2_LO, e);
}

// numpy pairwise_sum order for 64 elements (identical to R4..R10)
__device__ __forceinline__ float pairwise_np(float v, int lane) {
    float c = v;
    #pragma unroll
    for (int i = 1; i < 8; ++i)
        c = c + __shfl(v, (lane + 8 * i) & 63);
    float r0 = readlane_f(c, 0), r1 = readlane_f(c, 1);
    float r2 = readlane_f(c, 2), r3 = readlane_f(c, 3);
    float r4 = readlane_f(c, 4), r5 = readlane_f(c, 5);
    float r6 = readlane_f(c, 6), r7 = readlane_f(c, 7);
    return ((r0 + r1) + (r2 + r3)) + ((r4 + r5) + (r6 + r7));
}

__global__ __launch_bounds__(PORB)
__attribute__((amdgpu_waves_per_eu(1, 1)))
void sinkhorn_kernel(
    const float* __restrict__ n_in,
    const float* __restrict__ beta_ptr,
    const int*   __restrict__ iters_ptr,
    float*       __restrict__ out)
{
    const int b    = blockIdx.x;                // pair index
    const int lane = threadIdx.x;

    const float beta    = beta_ptr[0];
    const int   n_iters = iters_ptr[0];
    const float nb      = -beta;
    const float inv_beta = rcp_nr(beta);

    __shared__ __align__(16) float t_sh[2 * PORB];  // A: [0..63], B: [64..127]

    const int baseA = (2 * b) * PORB;
    const int baseB = (2 * b + 1) * PORB;
    const float npA = n_in[baseA + lane];
    const float npB = n_in[baseB + lane];

    // ---- setup per system (verbatim R10 order) ----
    const float srtA = pairwise_np(npA, lane);
    const float srtB = pairwise_np(npB, lane);
    const float nnA  = (npA * rcp_nr(srtA)) * (float)NPART;
    const float nnB  = (npB * rcp_nr(srtB)) * (float)NPART;
    const float snnA = pairwise_np(nnA, lane);
    const float snnB = pairwise_np(nnB, lane);
    const float isnA = rcp_nr(snnA);
    const float isnB = rcp_nr(snnB);
    const float ratA = nnA * rcp_nr(1.0f - nnA);
    const float ratB = nnB * rcp_nr(1.0f - nnB);
    float epsA = (-ln_acc(ratA)) * inv_beta;
    float epsB = (-ln_acc(ratB)) * inv_beta;

    // per-lane constants for the C_k block (R10 mapping, shared A/B)
    const float kf    = (float)((lane & 31) + 1);
    const float mk    = nb * kf;
    const int   jbase = (lane & 32) >> 3;       // 0 (half0) or 4 (half1)
    const int   q4    = jbase >> 2;             // float4-index offset: 0 or 1
    (void)kf;

    for (int it = 0; it < n_iters; ++it) {
        // ---- stage both systems' eps (barrier-bracketed fences) ----
        __syncthreads();
        t_sh[lane]        = epsA;
        t_sh[PORB + lane] = epsB;
        __syncthreads();

        const float4* t4 = reinterpret_cast<const float4*>(t_sh);

        // ================= system A: C-block (verbatim R10) =============
        float4 v4A[8];
        #pragma unroll
        for (int i = 0; i < 8; ++i) v4A[i] = t4[2 * i + q4];
        float accA[4];
        #pragma unroll
        for (int i = 0; i < 8; ++i) {
            const float e0 = exp_acc(mk * v4A[i].x);
            const float e1 = exp_acc(mk * v4A[i].y);
            const float e2 = exp_acc(mk * v4A[i].z);
            const float e3 = exp_acc(mk * v4A[i].w);
            if (i == 0) { accA[0] = e0; accA[1] = e1; accA[2] = e2; accA[3] = e3; }
            else        { accA[0] += e0; accA[1] += e1; accA[2] += e2; accA[3] += e3; }
        }
        float shA = (accA[0] + accA[1]) + (accA[2] + accA[3]);
        float CfA = shA + __shfl_xor(shA, 32);
        const float c1A = readlane_f(CfA, 0);
        const float prevCA = __shfl(CfA, (lane - 1) & 63);
        const float EA     = CfA * rcp_nr(prevCA);
        float ErA[NPART];
        #pragma unroll
        for (int s = 1; s < NPART; ++s) {
            ErA[s] = __shfl(EA, (lane + 1 - s) & 63);
            asm volatile("" : "+v"(ErA[s]));
        }

        // ================= system B: C-block (verbatim R10) =============
        float4 v4B[8];
        #pragma unroll
        for (int i = 0; i < 8; ++i) v4B[i] = t4[16 + 2 * i + q4];
        float accB[4];
        #pragma unroll
        for (int i = 0; i < 8; ++i) {
            const float e0 = exp_acc(mk * v4B[i].x);
            const float e1 = exp_acc(mk * v4B[i].y);
            const float e2 = exp_acc(mk * v4B[i].z);
            const float e3 = exp_acc(mk * v4B[i].w);
            if (i == 0) { accB[0] = e0; accB[1] = e1; accB[2] = e2; accB[3] = e3; }
            else        { accB[0] += e0; accB[1] += e1; accB[2] += e2; accB[3] += e3; }
        }
        float shB = (accB[0] + accB[1]) + (accB[2] + accB[3]);
        float CfB = shB + __shfl_xor(shB, 32);
        const float c1B = readlane_f(CfB, 0);
        const float prevCB = __shfl(CfB, (lane - 1) & 63);
        const float EB     = CfB * rcp_nr(prevCB);
        float ErB[NPART];
        #pragma unroll
        for (int s = 1; s < NPART; ++s) {
            ErB[s] = __shfl(EB, (lane + 1 - s) & 63);
            asm volatile("" : "+v"(ErB[s]));
        }

        // ---- aux inputs (depend only on eps) ----
        const float xA = exp_acc(nb * epsA);
        const float xB = exp_acc(nb * epsB);

        // ======== system A: fused sweep + aux (verbatim R12 form) =======
        float y30A, Qp1A, invQ31A;
        {
            const float invQ0 = rcp_nr(c1A);
            float prev = 1.0f - (xA * invQ0) * 1.0f;
            float y30 = 0.0f;
            float invQprev = invQ0;
            float p = 1.0f;
            #pragma unroll
            for (int s = 1; s < NPART; ++s) {
                const float d = ErA[s] * invQprev;
                const float m = d * p;
                p = 1.0f - m;
                const float ps = readlane_f(p, s);
                const float invQs = (float)(s + 1) * rcp_nr(c1A * ps);
                const float a = (xA * invQs) * prev;
                prev = 1.0f - a;
                if (s == NPART - 2) y30 = prev;
                invQprev = invQs;
            }
            y30A = y30; Qp1A = prev; invQ31A = invQprev;
        }

        // ======== system B: fused sweep + aux (verbatim R12 form) =======
        float y30B, Qp1B, invQ31B;
        {
            const float invQ0 = rcp_nr(c1B);
            float prev = 1.0f - (xB * invQ0) * 1.0f;
            float y30 = 0.0f;
            float invQprev = invQ0;
            float p = 1.0f;
            #pragma unroll
            for (int s = 1; s < NPART; ++s) {
                const float d = ErB[s] * invQprev;
                const float m = d * p;
                p = 1.0f - m;
                const float ps = readlane_f(p, s);
                const float invQs = (float)(s + 1) * rcp_nr(c1B * ps);
                const float a = (xB * invQs) * prev;
                prev = 1.0f - a;
                if (s == NPART - 2) y30 = prev;
                invQprev = invQs;
            }
            y30B = y30; Qp1B = prev; invQ31B = invQprev;
        }

        // ---- update + normalize per system (verbatim R10) ----
        const float Qp0A = y30A * invQ31A;
        const float Qp0B = y30B * invQ31B;
        const float qA = (ratA * Qp1A) * rcp_nr(Qp0A);
        const float qB = (ratB * Qp1B) * rcp_nr(Qp0B);
        const float enA = (-ln_acc(qA)) * inv_beta;
        const float enB = (-ln_acc(qB)) * inv_beta;

        const float WA = pairwise_np(nnA * enA, lane);
        const float WB = pairwise_np(nnB * enB, lane);
        epsA = enA - (WA * isnA);
        epsB = enB - (WB * isnB);
    }

    out[baseA + lane] = epsA;
    out[baseB + lane] = epsB;
}

extern "C" void kernel_launch(void* const* d_in, const int* in_sizes, int n_in,
                              void* d_out, int out_size, void* d_ws, size_t ws_size,
                              hipStream_t stream) {
    const float* n_ptr    = (const float*)d_in[0];
    const float* beta_ptr = (const float*)d_in[1];
    const int*   it_ptr   = (const int*)d_in[2];
    float*       out      = (float*)d_out;

    const int B = in_sizes[0] / PORB;   // 2048 systems
    sinkhorn_kernel<<<B / 2, PORB, 0, stream>>>(n_ptr, beta_ptr, it_ptr, out);
}

// Round 16
// 119.664 us; speedup vs baseline: 1.1228x; 1.1228x over previous
//
#include <hip/hip_runtime.h>

// Sinkhorn fixed-point for fermionic canonical ensembles.
// B=2048 systems, P=64 orbitals, N_PART=32, n_iters from d_in[2].
//
// R15: PHASE-SHIFTED SOFTWARE PIPELINE, MANUALLY INTERLEAVED.
// R14 (auto-interleave of duplicated bodies) regressed: scheduler followed
// source order, two sweeps ran serially. R12 showed the scheduler DOES
// fill stalls with textually-adjacent independent ops. So: one wave owns
// systems A,B (full 64-lane R10 mappings each), pipelined half-iteration
// out of phase; the OTHER system's C-block exps are placed INSIDE the
// 31-step sweep loop (1 exp_acc per step) as chain-independent filler.
//   prologue: C_A(0) -> E_A, ErA
//   iter: phase1: sweep+aux A + C_B filler; E_B/ErB; epilogue A; stage epsA
//         phase2: sweep+aux B + C_A(it+1) filler; E_A/ErA; epilogue B; stage epsB
// Last iter's C_A(n_iters) is wasted-but-free (occupies stall slots only).
// Per-system fp sequences/orders VERBATIM R10/R12 (accumulator t=4i+jj
// ascending-i order == R10's loop). CANARY: absmax exactly 0.015625.
// Posture: contract(off), Cody-Waite exp/log, ~1ulp rcp_nr, Er pins,
// waves_per_eu(1,1), barrier-bracketed LDS staging (1 wave/block).

#pragma clang fp contract(off)

#define NPART 32
#define PORB  64

#define L2E_HI 1.44269502162933349609375f
#define L2E_LO 1.9259629911266175e-08f
#define LN2_HI 0.69314718246459960938f
#define LN2_LO -1.9046542121259175e-09f
#define LN2F   0.6931471805599453f

__device__ __forceinline__ float readlane_f(float v, int srclane) {
    return __int_as_float(__builtin_amdgcn_readlane(__float_as_int(v), srclane));
}

__device__ __forceinline__ float rcp_nr(float d) {
    float r = __builtin_amdgcn_rcpf(d);
    float e = fmaf(-d, r, 1.0f);
    return fmaf(r, e, r);
}

__device__ __forceinline__ float exp_acc(float arg) {
    float p    = arg * L2E_HI;
    float perr = fmaf(arg, L2E_HI, -p);
    float c    = fmaf(arg, L2E_LO, perr);
    float e0   = __builtin_amdgcn_exp2f(p);
    return fmaf(e0, c * LN2F, e0);
}

__device__ __forceinline__ float ln_acc(float x) {
    float l2 = __log2f(x);
    float p  = l2 * LN2_HI;
    float e  = fmaf(l2, LN2_HI, -p);
    return p + fmaf(l2, LN2_LO, e);
}

// numpy pairwise_sum order for 64 elements (identical to R4..R12)
__device__ __forceinline__ float pairwise_np(float v, int lane) {
    float c = v;
    #pragma unroll
    for (int i = 1; i < 8; ++i)
        c = c + __shfl(v, (lane + 8 * i) & 63);
    float r0 = readlane_f(c, 0), r1 = readlane_f(c, 1);
    float r2 = readlane_f(c, 2), r3 = readlane_f(c, 3);
    float r4 = readlane_f(c, 4), r5 = readlane_f(c, 5);
    float r6 = readlane_f(c, 6), r7 = readlane_f(c, 7);
    return ((r0 + r1) + (r2 + r3)) + ((r4 + r5) + (r6 + r7));
}

// compile-time float4 component select (folds under full unroll)
__device__ __forceinline__ float f4c(const float4& v, int j) {
    return j == 0 ? v.x : (j == 1 ? v.y : (j == 2 ? v.z : v.w));
}

__global__ __launch_bounds__(PORB)
__attribute__((amdgpu_waves_per_eu(1, 1)))
void sinkhorn_kernel(
    const float* __restrict__ n_in,
    const float* __restrict__ beta_ptr,
    const int*   __restrict__ iters_ptr,
    float*       __restrict__ out)
{
    const int b    = blockIdx.x;                // pair index
    const int lane = threadIdx.x;

    const float beta    = beta_ptr[0];
    const int   n_iters = iters_ptr[0];
    const float nb      = -beta;
    const float inv_beta = rcp_nr(beta);

    __shared__ __align__(16) float t_sh[2 * PORB];  // A: [0..63], B: [64..127]

    const int baseA = (2 * b) * PORB;
    const int baseB = (2 * b + 1) * PORB;
    const float npA = n_in[baseA + lane];
    const float npB = n_in[baseB + lane];

    // ---- setup per system (verbatim R10 order) ----
    const float srtA = pairwise_np(npA, lane);
    const float srtB = pairwise_np(npB, lane);
    const float nnA  = (npA * rcp_nr(srtA)) * (float)NPART;
    const float nnB  = (npB * rcp_nr(srtB)) * (float)NPART;
    const float snnA = pairwise_np(nnA, lane);
    const float snnB = pairwise_np(nnB, lane);
    const float isnA = rcp_nr(snnA);
    const float isnB = rcp_nr(snnB);
    const float ratA = nnA * rcp_nr(1.0f - nnA);
    const float ratB = nnB * rcp_nr(1.0f - nnB);
    float epsA = (-ln_acc(ratA)) * inv_beta;
    float epsB = (-ln_acc(ratB)) * inv_beta;

    // per-lane constants for the C_k block (R10 mapping, shared A/B)
    const float mk = nb * (float)((lane & 31) + 1);
    const int   q4 = (lane & 32) >> 5;          // float4-index offset: 0 or 1

    const float4* t4 = reinterpret_cast<const float4*>(t_sh);

    // ---- prologue: stage both eps; C-block A(0) (verbatim R10) ----
    __syncthreads();
    t_sh[lane]        = epsA;
    t_sh[PORB + lane] = epsB;
    __syncthreads();

    float ErA[NPART];
    float c1A;
    {
        float4 v4[8];
        #pragma unroll
        for (int i = 0; i < 8; ++i) v4[i] = t4[2 * i + q4];
        float acc[4];
        #pragma unroll
        for (int i = 0; i < 8; ++i) {
            const float e0 = exp_acc(mk * v4[i].x);
            const float e1 = exp_acc(mk * v4[i].y);
            const float e2 = exp_acc(mk * v4[i].z);
            const float e3 = exp_acc(mk * v4[i].w);
            if (i == 0) { acc[0] = e0; acc[1] = e1; acc[2] = e2; acc[3] = e3; }
            else        { acc[0] += e0; acc[1] += e1; acc[2] += e2; acc[3] += e3; }
        }
        const float sh = (acc[0] + acc[1]) + (acc[2] + acc[3]);
        const float Cf = sh + __shfl_xor(sh, 32);
        c1A = readlane_f(Cf, 0);
        const float prevC = __shfl(Cf, (lane - 1) & 63);
        const float E     = Cf * rcp_nr(prevC);
        #pragma unroll
        for (int s = 1; s < NPART; ++s) {
            ErA[s] = __shfl(E, (lane + 1 - s) & 63);
            asm volatile("" : "+v"(ErA[s]));
        }
    }

    float ErB[NPART];
    float c1B;

    for (int it = 0; it < n_iters; ++it) {
        // ==================== phase 1: A sweeps, B's C-block fills =======
        {
            const float xA = exp_acc(nb * epsA);
            float4 vB[8];
            #pragma unroll
            for (int i = 0; i < 8; ++i) vB[i] = t4[16 + 2 * i + q4];

            float accB[4];
            float y30A, Qp1A, invQ31A;
            {
                const float invQ0 = rcp_nr(c1A);
                float prev = 1.0f - (xA * invQ0) * 1.0f;
                float y30 = 0.0f;
                float invQprev = invQ0;
                float p = 1.0f;
                #pragma unroll
                for (int s = 1; s < NPART; ++s) {
                    // --- sweep+aux A, verbatim R12 chain ---
                    const float d = ErA[s] * invQprev;
                    const float m = d * p;
                    p = 1.0f - m;
                    const float ps = readlane_f(p, s);
                    const float invQs = (float)(s + 1) * rcp_nr(c1A * ps);
                    const float a = (xA * invQs) * prev;
                    prev = 1.0f - a;
                    if (s == NPART - 2) y30 = prev;
                    invQprev = invQs;
                    // --- filler: C_B term t=s-1 (chain-independent) ---
                    const int t = s - 1, i = t >> 2, jj = t & 3;
                    const float ev = exp_acc(mk * f4c(vB[i], jj));
                    if (i == 0) accB[jj] = ev; else accB[jj] += ev;
                }
                y30A = y30; Qp1A = prev; invQ31A = invQprev;
            }
            accB[3] += exp_acc(mk * vB[7].w);          // t=31
            const float shB = (accB[0] + accB[1]) + (accB[2] + accB[3]);
            const float CfB = shB + __shfl_xor(shB, 32);
            c1B = readlane_f(CfB, 0);
            const float prevCB = __shfl(CfB, (lane - 1) & 63);
            const float EB     = CfB * rcp_nr(prevCB);
            #pragma unroll
            for (int s = 1; s < NPART; ++s) {
                ErB[s] = __shfl(EB, (lane + 1 - s) & 63);
                asm volatile("" : "+v"(ErB[s]));
            }
            // epilogue A (verbatim R10/R12)
            const float Qp0A = y30A * invQ31A;
            const float qA = (ratA * Qp1A) * rcp_nr(Qp0A);
            const float enA = (-ln_acc(qA)) * inv_beta;
            const float WA = pairwise_np(nnA * enA, lane);
            epsA = enA - (WA * isnA);
        }
        __syncthreads();
        t_sh[lane] = epsA;                              // stage A(it+1)
        __syncthreads();

        // ==================== phase 2: B sweeps, A's C-block fills =======
        {
            const float xB = exp_acc(nb * epsB);
            float4 vA[8];
            #pragma unroll
            for (int i = 0; i < 8; ++i) vA[i] = t4[2 * i + q4];

            float accA[4];
            float y30B, Qp1B, invQ31B;
            {
                const float invQ0 = rcp_nr(c1B);
                float prev = 1.0f - (xB * invQ0) * 1.0f;
                float y30 = 0.0f;
                float invQprev = invQ0;
                float p = 1.0f;
                #pragma unroll
                for (int s = 1; s < NPART; ++s) {
                    // --- sweep+aux B, verbatim R12 chain ---
                    const float d = ErB[s] * invQprev;
                    const float m = d * p;
                    p = 1.0f - m;
                    const float ps = readlane_f(p, s);
                    const float invQs = (float)(s + 1) * rcp_nr(c1B * ps);
                    const float a = (xB * invQs) * prev;
                    prev = 1.0f - a;
                    if (s == NPART - 2) y30 = prev;
                    invQprev = invQs;
                    // --- filler: C_A(it+1) term t=s-1 ---
                    const int t = s - 1, i = t >> 2, jj = t & 3;
                    const float ev = exp_acc(mk * f4c(vA[i], jj));
                    if (i == 0) accA[jj] = ev; else accA[jj] += ev;
                }
                y30B = y30; Qp1B = prev; invQ31B = invQprev;
            }
            accA[3] += exp_acc(mk * vA[7].w);          // t=31
            const float shA = (accA[0] + accA[1]) + (accA[2] + accA[3]);
            const float CfA = shA + __shfl_xor(shA, 32);
            c1A = readlane_f(CfA, 0);
            const float prevCA = __shfl(CfA, (lane - 1) & 63);
            const float EA     = CfA * rcp_nr(prevCA);
            #pragma unroll
            for (int s = 1; s < NPART; ++s) {
                ErA[s] = __shfl(EA, (lane + 1 - s) & 63);
                asm volatile("" : "+v"(ErA[s]));
            }
            // epilogue B (verbatim R10/R12)
            const float Qp0B = y30B * invQ31B;
            const float qB = (ratB * Qp1B) * rcp_nr(Qp0B);
            const float enB = (-ln_acc(qB)) * inv_beta;
            const float WB = pairwise_np(nnB * enB, lane);
            epsB = enB - (WB * isnB);
        }
        __syncthreads();
        t_sh[PORB + lane] = epsB;                       // stage B(it+1)
        __syncthreads();
    }

    out[baseA + lane] = epsA;
    out[baseB + lane] = epsB;
}

extern "C" void kernel_launch(void* const* d_in, const int* in_sizes, int n_in,
                              void* d_out, int out_size, void* d_ws, size_t ws_size,
                              hipStream_t stream) {
    const float* n_ptr    = (const float*)d_in[0];
    const float* beta_ptr = (const float*)d_in[1];
    const int*   it_ptr   = (const int*)d_in[2];
    float*       out      = (float*)d_out;

    const int B = in_sizes[0] / PORB;   // 2048 systems
    sinkhorn_kernel<<<B / 2, PORB, 0, stream>>>(n_ptr, beta_ptr, it_ptr, out);
}

// Round 17
// 110.594 us; speedup vs baseline: 1.2149x; 1.0820x over previous
//
#include <hip/hip_runtime.h>

// Sinkhorn fixed-point for fermionic canonical ensembles.
// B=2048 systems, P=64 orbitals, N_PART=32, n_iters from d_in[2].
//
// R16 = R12 (best together with R11: 60.7-61.4us rocprof, absmax 0.015625)
// with the two per-iteration __syncthreads() replaced by ZERO-RUNTIME
// compiler fences. Rationale: one wave per block => the DS pipe retires a
// wave's LDS ops in issue order (lgkmcnt is in-order for DS), so a ds_read
// issued after a ds_write always observes it -- the ONLY hazard is compiler
// reordering (R1's NaN). asm volatile("" ::: "memory") pins the order at
// compile time and deletes the s_waitcnt lgkmcnt(0)/vmcnt(0) + s_barrier
// drains (~150-300 cyc/iter). eps staging moved into the epilogue (written
// where produced). NO fp op changes -> trajectory bit-identical.
// CANARY: absmax must be exactly 0.015625.
// Structure recap (R11/R12, proven optimal across R13-R15 attempts):
// pack-2 lane-split (A=lanes 0-31, B=32-63), shared 31-step sweep serving
// both systems, aux fused into the sweep, Er preload + volatile pins,
// contract(off), Cody-Waite exp/log, ~1ulp rcp_nr, numpy pairwise order,
// waves_per_eu(1,1).

#pragma clang fp contract(off)

#define NPART 32
#define PORB  64

#define L2E_HI 1.44269502162933349609375f
#define L2E_LO 1.9259629911266175e-08f
#define LN2_HI 0.69314718246459960938f
#define LN2_LO -1.9046542121259175e-09f
#define LN2F   0.6931471805599453f

// zero-runtime ordering fence: stops compiler reordering of LDS ops.
// HW needs nothing: single wave per block + in-order DS pipe.
#define LDS_FENCE() asm volatile("" ::: "memory")

__device__ __forceinline__ float readlane_f(float v, int srclane) {
    return __int_as_float(__builtin_amdgcn_readlane(__float_as_int(v), srclane));
}

// reciprocal: v_rcp_f32 + one Newton step => ~0.5-1 ulp
__device__ __forceinline__ float rcp_nr(float d) {
    float r = __builtin_amdgcn_rcpf(d);
    float e = fmaf(-d, r, 1.0f);
    return fmaf(r, e, r);
}

// e^arg with Cody-Waite correction (<=1.5 ulp), arg pre-rounded like numpy
__device__ __forceinline__ float exp_acc(float arg) {
    float p    = arg * L2E_HI;
    float perr = fmaf(arg, L2E_HI, -p);
    float c    = fmaf(arg, L2E_LO, perr);
    float e0   = __builtin_amdgcn_exp2f(p);
    return fmaf(e0, c * LN2F, e0);
}

// ln(x) = log2(x)*ln2 with split constant (~1.5 ulp)
__device__ __forceinline__ float ln_acc(float x) {
    float l2 = __log2f(x);
    float p  = l2 * LN2_HI;
    float e  = fmaf(l2, LN2_HI, -p);
    return p + fmaf(l2, LN2_LO, e);
}

// shuffle within the lane's own 32-lane half
__device__ __forceinline__ float shfl32(float v, int idx, int hbit) {
    return __shfl(v, (idx & 31) | hbit);
}

// numpy pairwise_sum over one system's 64 orbitals (identical to R11/R12)
__device__ __forceinline__ float red_np(float v0, float v1, int l32, int hbit) {
    float c = v0;
    c = c + shfl32(v0, l32 + 8,  hbit);
    c = c + shfl32(v0, l32 + 16, hbit);
    c = c + shfl32(v0, l32 + 24, hbit);
    c = c + v1;
    c = c + shfl32(v1, l32 + 8,  hbit);
    c = c + shfl32(v1, l32 + 16, hbit);
    c = c + shfl32(v1, l32 + 24, hbit);
    const float ta = ((readlane_f(c, 0) + readlane_f(c, 1)) +
                      (readlane_f(c, 2) + readlane_f(c, 3))) +
                     ((readlane_f(c, 4) + readlane_f(c, 5)) +
                      (readlane_f(c, 6) + readlane_f(c, 7)));
    const float tb = ((readlane_f(c, 32) + readlane_f(c, 33)) +
                      (readlane_f(c, 34) + readlane_f(c, 35))) +
                     ((readlane_f(c, 36) + readlane_f(c, 37)) +
                      (readlane_f(c, 38) + readlane_f(c, 39)));
    return hbit ? tb : ta;
}

__global__ __launch_bounds__(PORB)
__attribute__((amdgpu_waves_per_eu(1, 1)))
void sinkhorn_kernel(
    const float* __restrict__ n_in,
    const float* __restrict__ beta_ptr,
    const int*   __restrict__ iters_ptr,
    float*       __restrict__ out)
{
    const int b    = blockIdx.x;                // pair index
    const int lane = threadIdx.x;
    const int l32  = lane & 31;
    const int hbit = lane & 32;                 // 0 (system A) / 32 (system B)
    const int h    = hbit >> 5;

    const float beta    = beta_ptr[0];
    const int   n_iters = iters_ptr[0];
    const float nb      = -beta;
    const float inv_beta = rcp_nr(beta);

    __shared__ __align__(16) float t_sh[2 * PORB];  // eps staging, 2 systems

    const int sysbase = (2 * b + h) * PORB;
    const float n0 = n_in[sysbase + l32];           // orbital l32
    const float n1 = n_in[sysbase + 32 + l32];      // orbital l32+32

    // ---- setup: nn, snn, ratio, eps0 (per-system values == R11/R12) ----
    const float srt  = red_np(n0, n1, l32, hbit);
    const float isrt = rcp_nr(srt);
    const float nn0  = (n0 * isrt) * (float)NPART;
    const float nn1  = (n1 * isrt) * (float)NPART;
    const float snn  = red_np(nn0, nn1, l32, hbit);
    const float inv_snn = rcp_nr(snn);
    const float ratio0  = nn0 * rcp_nr(1.0f - nn0);
    const float ratio1  = nn1 * rcp_nr(1.0f - nn1);
    float eps0 = (-ln_acc(ratio0)) * inv_beta;
    float eps1 = (-ln_acc(ratio1)) * inv_beta;

    const float kf = (float)(l32 + 1);              // this lane's k
    const float mk = nb * kf;

    // ---- prologue staging: write eps(0); fence orders it before reads ----
    t_sh[2 * hbit + l32]      = eps0;               // 2*hbit == h*64
    t_sh[2 * hbit + 32 + l32] = eps1;
    LDS_FENCE();

    for (int it = 0; it < n_iters; ++it) {
        // (reads below are ordered after the preceding writes by the fence)

        // ---- C_k: lane k-1 of each half builds all 8 numpy accumulators
        // (identical values/order to R11/R12); 2x ds_read_b128 per i,
        // uniform address per half => broadcast, conflict-free.
        const float4* t4 = reinterpret_cast<const float4*>(t_sh);
        float acc[8];
        #pragma unroll
        for (int i = 0; i < 8; ++i) {
            const float4 va = t4[(h << 4) + 2 * i];      // eps[8i .. 8i+3]
            const float4 vb = t4[(h << 4) + 2 * i + 1];  // eps[8i+4 .. 8i+7]
            const float e0 = exp_acc(mk * va.x);
            const float e1 = exp_acc(mk * va.y);
            const float e2 = exp_acc(mk * va.z);
            const float e3 = exp_acc(mk * va.w);
            const float e4 = exp_acc(mk * vb.x);
            const float e5 = exp_acc(mk * vb.y);
            const float e6 = exp_acc(mk * vb.z);
            const float e7 = exp_acc(mk * vb.w);
            if (i == 0) {
                acc[0] = e0; acc[1] = e1; acc[2] = e2; acc[3] = e3;
                acc[4] = e4; acc[5] = e5; acc[6] = e6; acc[7] = e7;
            } else {
                acc[0] += e0; acc[1] += e1; acc[2] += e2; acc[3] += e3;
                acc[4] += e4; acc[5] += e5; acc[6] += e6; acc[7] += e7;
            }
        }
        const float Cfull = ((acc[0] + acc[1]) + (acc[2] + acc[3])) +
                            ((acc[4] + acc[5]) + (acc[6] + acc[7]));
        // lane hbit + (k-1) holds C[k] of its system

        const float c1A = readlane_f(Cfull, 0);
        const float c1B = readlane_f(Cfull, 32);
        const float c1v = hbit ? c1B : c1A;          // per-half C[1]

        // E[i] = C[i+1]/C[i] (l32==0 junk, never consumed by live lanes)
        const float prevC = __shfl(Cfull, ((l32 - 1) & 31) | hbit);
        const float E     = Cfull * rcp_nr(prevC);

        // ---- preload + pin the 31 E-gathers (R8 win) ----
        float Er[NPART];
        #pragma unroll
        for (int s = 1; s < NPART; ++s) {
            Er[s] = __shfl(E, ((l32 + 1 - s) & 31) | hbit);
            asm volatile("" : "+v"(Er[s]));          // schedule pin only
        }

        // ---- aux inputs, hoisted (depend only on eps) ----
        const float x0 = exp_acc(nb * eps0);
        const float x1 = exp_acc(nb * eps1);

        // ---- fused sweep + aux (verbatim R12: shared 31-step traversal
        // serving both systems; aux step s right after invQ[s] exists) ----
        const float invQ0 = rcp_nr(c1v);
        float prev0, prev1;
        {
            const float a0 = (x0 * invQ0) * 1.0f;
            prev0 = 1.0f - a0;
            const float a1 = (x1 * invQ0) * 1.0f;
            prev1 = 1.0f - a1;
        }
        float y30_0 = 0.0f, y30_1 = 0.0f;
        float invQprev = invQ0;                      // invQ[s-1] carry
        float p = 1.0f;
        #pragma unroll
        for (int s = 1; s < NPART; ++s) {
            const float d = Er[s] * invQprev;
            const float m = d * p;
            p = 1.0f - m;
            const float psA = readlane_f(p, s);
            const float psB = readlane_f(p, 32 + s);
            const float psv = hbit ? psB : psA;
            const float invQs = (float)(s + 1) * rcp_nr(c1v * psv);
            const float a0 = (x0 * invQs) * prev0;
            prev0 = 1.0f - a0;
            const float a1 = (x1 * invQs) * prev1;
            prev1 = 1.0f - a1;
            if (s == NPART - 2) { y30_0 = prev0; y30_1 = prev1; }
            invQprev = invQs;
        }
        const float invQ31 = invQprev;               // invQ[NPART-1]
        const float Qp1_0 = prev0,          Qp1_1 = prev1;
        const float Qp0_0 = y30_0 * invQ31;
        const float Qp0_1 = y30_1 * invQ31;

        // ---- update + normalize (identical to R11/R12) ----
        const float q0 = (ratio0 * Qp1_0) * rcp_nr(Qp0_0);
        const float q1 = (ratio1 * Qp1_1) * rcp_nr(Qp0_1);
        const float en0 = (-ln_acc(q0)) * inv_beta;
        const float en1 = (-ln_acc(q1)) * inv_beta;

        const float W = red_np(nn0 * en0, nn1 * en1, l32, hbit);
        const float corr = W * inv_snn;
        eps0 = en0 - corr;
        eps1 = en1 - corr;

        // ---- stage eps(it+1) where produced; fences order the LDS ops:
        // (this iter's reads) < (these writes) < (next iter's reads) ----
        LDS_FENCE();                                 // reads above first
        t_sh[2 * hbit + l32]      = eps0;
        t_sh[2 * hbit + 32 + l32] = eps1;
        LDS_FENCE();                                 // writes before next reads
    }

    out[sysbase + l32]      = eps0;
    out[sysbase + 32 + l32] = eps1;
}

extern "C" void kernel_launch(void* const* d_in, const int* in_sizes, int n_in,
                              void* d_out, int out_size, void* d_ws, size_t ws_size,
                              hipStream_t stream) {
    const float* n_ptr    = (const float*)d_in[0];
    const float* beta_ptr = (const float*)d_in[1];
    const int*   it_ptr   = (const int*)d_in[2];
    float*       out      = (float*)d_out;

    const int B = in_sizes[0] / PORB;   // 2048 systems
    sinkhorn_kernel<<<B / 2, PORB, 0, stream>>>(n_ptr, beta_ptr, it_ptr, out);
}

// Round 18
// 109.872 us; speedup vs baseline: 1.2229x; 1.0066x over previous
//
#include <hip/hip_runtime.h>

// Sinkhorn fixed-point for fermionic canonical ensembles.
// B=2048 systems, P=64 orbitals, N_PART=32, n_iters from d_in[2].
//
// R17 = R11 VERBATIM (the measured optimum: 60.7us rocprof / 109.9us bench,
// absmax 0.015625). Rounds 12-16 bracketed the plateau: aux fusion (R12,
// +0.7us -- compiler already interleaves), phase-parallel duplication
// (R13/14, +26us -- scheduler won't cross-interleave), manual pipelining
// (R15, +12us -- broke the shared sweep), barrier->fence staging (R16,
// +2.4us). Structural floor: per iter, issue ~4150 cyc + ~3100 cyc of
// unfillable chain stalls at 1 wave/SIMD; a second HW wave is impossible
// (2048 systems / 2-per-wave = 1024 waves = exactly 1/SIMD; pack-1 with 2
// waves/SIMD measured worse, 67.7us) and all value-changing shortcuts are
// forbidden (accuracy budget spent: threshold 0.0214, draw 0.0156,
// value changes re-roll a +-3x draw).
// Structure: pack-2 lane-split (A=lanes 0-31, B=32-63); one shared 31-step
// lane-pipelined Q sweep serves both systems; aux 2 orbitals/lane;
// Er preload + volatile pins; contract(off); Cody-Waite exp/log; ~1ulp
// rcp_nr; numpy pairwise-sum order; waves_per_eu(1,1); barrier-bracketed
// LDS staging. CANARY: absmax must be exactly 0.015625.

#pragma clang fp contract(off)

#define NPART 32
#define PORB  64

#define L2E_HI 1.44269502162933349609375f
#define L2E_LO 1.9259629911266175e-08f
#define LN2_HI 0.69314718246459960938f
#define LN2_LO -1.9046542121259175e-09f
#define LN2F   0.6931471805599453f

__device__ __forceinline__ float readlane_f(float v, int srclane) {
    return __int_as_float(__builtin_amdgcn_readlane(__float_as_int(v), srclane));
}

// reciprocal: v_rcp_f32 + one Newton step => ~0.5-1 ulp
__device__ __forceinline__ float rcp_nr(float d) {
    float r = __builtin_amdgcn_rcpf(d);
    float e = fmaf(-d, r, 1.0f);
    return fmaf(r, e, r);
}

// e^arg with Cody-Waite correction (<=1.5 ulp), arg pre-rounded like numpy
__device__ __forceinline__ float exp_acc(float arg) {
    float p    = arg * L2E_HI;
    float perr = fmaf(arg, L2E_HI, -p);
    float c    = fmaf(arg, L2E_LO, perr);
    float e0   = __builtin_amdgcn_exp2f(p);
    return fmaf(e0, c * LN2F, e0);
}

// ln(x) = log2(x)*ln2 with split constant (~1.5 ulp)
__device__ __forceinline__ float ln_acc(float x) {
    float l2 = __log2f(x);
    float p  = l2 * LN2_HI;
    float e  = fmaf(l2, LN2_HI, -p);
    return p + fmaf(l2, LN2_LO, e);
}

// shuffle within the lane's own 32-lane half
__device__ __forceinline__ float shfl32(float v, int idx, int hbit) {
    return __shfl(v, (idx & 31) | hbit);
}

// numpy pairwise_sum over one system's 64 orbitals, values held as
// (v0,v1) on 32 lanes per half (identical to R11).
__device__ __forceinline__ float red_np(float v0, float v1, int l32, int hbit) {
    float c = v0;
    c = c + shfl32(v0, l32 + 8,  hbit);
    c = c + shfl32(v0, l32 + 16, hbit);
    c = c + shfl32(v0, l32 + 24, hbit);
    c = c + v1;
    c = c + shfl32(v1, l32 + 8,  hbit);
    c = c + shfl32(v1, l32 + 16, hbit);
    c = c + shfl32(v1, l32 + 24, hbit);
    const float ta = ((readlane_f(c, 0) + readlane_f(c, 1)) +
                      (readlane_f(c, 2) + readlane_f(c, 3))) +
                     ((readlane_f(c, 4) + readlane_f(c, 5)) +
                      (readlane_f(c, 6) + readlane_f(c, 7)));
    const float tb = ((readlane_f(c, 32) + readlane_f(c, 33)) +
                      (readlane_f(c, 34) + readlane_f(c, 35))) +
                     ((readlane_f(c, 36) + readlane_f(c, 37)) +
                      (readlane_f(c, 38) + readlane_f(c, 39)));
    return hbit ? tb : ta;
}

__global__ __launch_bounds__(PORB)
__attribute__((amdgpu_waves_per_eu(1, 1)))
void sinkhorn_kernel(
    const float* __restrict__ n_in,
    const float* __restrict__ beta_ptr,
    const int*   __restrict__ iters_ptr,
    float*       __restrict__ out)
{
    const int b    = blockIdx.x;                // pair index
    const int lane = threadIdx.x;
    const int l32  = lane & 31;
    const int hbit = lane & 32;                 // 0 (system A) / 32 (system B)
    const int h    = hbit >> 5;

    const float beta    = beta_ptr[0];
    const int   n_iters = iters_ptr[0];
    const float nb      = -beta;
    const float inv_beta = rcp_nr(beta);

    __shared__ __align__(16) float t_sh[2 * PORB];  // eps staging, 2 systems

    const int sysbase = (2 * b + h) * PORB;
    const float n0 = n_in[sysbase + l32];           // orbital l32
    const float n1 = n_in[sysbase + 32 + l32];      // orbital l32+32

    // ---- setup: nn, snn, ratio, eps0 (per-system values == R10) ----
    const float srt  = red_np(n0, n1, l32, hbit);
    const float isrt = rcp_nr(srt);
    const float nn0  = (n0 * isrt) * (float)NPART;
    const float nn1  = (n1 * isrt) * (float)NPART;
    const float snn  = red_np(nn0, nn1, l32, hbit);
    const float inv_snn = rcp_nr(snn);
    const float ratio0  = nn0 * rcp_nr(1.0f - nn0);
    const float ratio1  = nn1 * rcp_nr(1.0f - nn1);
    float eps0 = (-ln_acc(ratio0)) * inv_beta;
    float eps1 = (-ln_acc(ratio1)) * inv_beta;

    const float kf = (float)(l32 + 1);              // this lane's k
    const float mk = nb * kf;

    for (int it = 0; it < n_iters; ++it) {
        // ---- stage both systems' eps (barrier-bracketed fences) ----
        __syncthreads();
        t_sh[2 * hbit + l32]      = eps0;           // 2*hbit == h*64
        t_sh[2 * hbit + 32 + l32] = eps1;
        __syncthreads();

        // ---- C_k: this lane computes its system's C_{l32+1} alone.
        // acc[jj] = numpy r[jj] (8 terms, sequential in i); reads are
        // 2x ds_read_b128 per i (uniform addr per half => broadcast).
        const float4* t4 = reinterpret_cast<const float4*>(t_sh);
        float acc[8];
        #pragma unroll
        for (int i = 0; i < 8; ++i) {
            const float4 va = t4[(h << 4) + 2 * i];      // eps[8i .. 8i+3]
            const float4 vb = t4[(h << 4) + 2 * i + 1];  // eps[8i+4 .. 8i+7]
            const float e0 = exp_acc(mk * va.x);
            const float e1 = exp_acc(mk * va.y);
            const float e2 = exp_acc(mk * va.z);
            const float e3 = exp_acc(mk * va.w);
            const float e4 = exp_acc(mk * vb.x);
            const float e5 = exp_acc(mk * vb.y);
            const float e6 = exp_acc(mk * vb.z);
            const float e7 = exp_acc(mk * vb.w);
            if (i == 0) {
                acc[0] = e0; acc[1] = e1; acc[2] = e2; acc[3] = e3;
                acc[4] = e4; acc[5] = e5; acc[6] = e6; acc[7] = e7;
            } else {
                acc[0] += e0; acc[1] += e1; acc[2] += e2; acc[3] += e3;
                acc[4] += e4; acc[5] += e5; acc[6] += e6; acc[7] += e7;
            }
        }
        const float Cfull = ((acc[0] + acc[1]) + (acc[2] + acc[3])) +
                            ((acc[4] + acc[5]) + (acc[6] + acc[7]));
        // lane hbit + (k-1) holds C[k] of its system

        const float c1A = readlane_f(Cfull, 0);
        const float c1B = readlane_f(Cfull, 32);
        const float c1v = hbit ? c1B : c1A;          // per-half C[1]

        // E[i] = C[i+1]/C[i] (l32==0 junk, never consumed by live lanes)
        const float prevC = __shfl(Cfull, ((l32 - 1) & 31) | hbit);
        const float E     = Cfull * rcp_nr(prevC);

        // ---- preload + pin the 31 E-gathers (R8 win) ----
        float Er[NPART];
        #pragma unroll
        for (int s = 1; s < NPART; ++s) {
            Er[s] = __shfl(E, ((l32 + 1 - s) & 31) | hbit);
            asm volatile("" : "+v"(Er[s]));          // schedule pin only
        }

        // ---- lane-pipelined Q sweep, both systems per traversal ----
        // invQ[s] = (s+1) * rcp_nr(c1 * ps)   (exact R5/R10 rounding)
        float invQ[NPART];
        invQ[0] = rcp_nr(c1v);
        float p = 1.0f;
        #pragma unroll
        for (int s = 1; s < NPART; ++s) {
            const float d = Er[s] * invQ[s - 1];
            const float m = d * p;
            p = 1.0f - m;
            const float psA = readlane_f(p, s);
            const float psB = readlane_f(p, 32 + s);
            const float psv = hbit ? psB : psA;
            invQ[s] = (float)(s + 1) * rcp_nr(c1v * psv);
        }

        // ---- aux: 2 orbitals/lane, two interleaved mul+sub chains ----
        const float x0 = exp_acc(nb * eps0);
        const float x1 = exp_acc(nb * eps1);
        float g0[NPART], g1[NPART];
        #pragma unroll
        for (int k = 0; k < NPART; ++k) { g0[k] = x0 * invQ[k];
                                          g1[k] = x1 * invQ[k]; }
        float prev0 = 1.0f, prev1 = 1.0f, y30_0 = 0.0f, y30_1 = 0.0f;
        #pragma unroll
        for (int k = 0; k < NPART; ++k) {
            const float m0 = g0[k] * prev0;
            const float m1 = g1[k] * prev1;
            prev0 = 1.0f - m0;
            prev1 = 1.0f - m1;
            if (k == NPART - 2) { y30_0 = prev0; y30_1 = prev1; }
        }
        const float Qp1_0 = prev0,                Qp1_1 = prev1;
        const float Qp0_0 = y30_0 * invQ[NPART - 1];
        const float Qp0_1 = y30_1 * invQ[NPART - 1];

        // ---- update + normalize (per-orbital, values == R10) ----
        const float q0 = (ratio0 * Qp1_0) * rcp_nr(Qp0_0);
        const float q1 = (ratio1 * Qp1_1) * rcp_nr(Qp0_1);
        const float en0 = (-ln_acc(q0)) * inv_beta;
        const float en1 = (-ln_acc(q1)) * inv_beta;

        const float W = red_np(nn0 * en0, nn1 * en1, l32, hbit);
        const float corr = W * inv_snn;
        eps0 = en0 - corr;
        eps1 = en1 - corr;
    }

    out[sysbase + l32]      = eps0;
    out[sysbase + 32 + l32] = eps1;
}

extern "C" void kernel_launch(void* const* d_in, const int* in_sizes, int n_in,
                              void* d_out, int out_size, void* d_ws, size_t ws_size,
                              hipStream_t stream) {
    const float* n_ptr    = (const float*)d_in[0];
    const float* beta_ptr = (const float*)d_in[1];
    const int*   it_ptr   = (const int*)d_in[2];
    float*       out      = (float*)d_out;

    const int B = in_sizes[0] / PORB;   // 2048 systems
    sinkhorn_kernel<<<B / 2, PORB, 0, stream>>>(n_ptr, beta_ptr, it_ptr, out);
}